// Round 7
// baseline (503.677 us; speedup 1.0000x reference)
//
#include <hip/hip_runtime.h>

typedef short short8 __attribute__((ext_vector_type(8)));
typedef float f32x16 __attribute__((ext_vector_type(16)));

// Problem constants
#define DIMV   64
#define NEMB   1024
#define NROWS  262144          // B*T = 2048*128
#define DECAYF 0.99f
#define OMDF   0.01f
#define EPSF   1e-5f
#define NSH    8               // bucket cursor shards (parallelize atomic drain)

// d_out layout (floats): quantize | loss | new_embed | new_cluster_size | new_embed_avg
#define OQ   0
#define OL   16777216
#define OE   16777217
#define ONC  16842753
#define OA   16843777
// EH/EL (bf16 split codebook, MFMA-B-fragment order) live in the d_out tail:
// written by vq_prep, read by vq_main, then overwritten by finalA/finalB.
#define OEH  16777216
#define OEL  (16777216 + 32768)

// d_ws layout (floats)
#define WS_E2     0        // 1024: ||e_k||^2
#define WS_CNT    1024     // 8192 ints: sharded cursors cnt[c + 1024*s]
#define WS_ESUM   9216     // 65536: embed_sum, K-MAJOR: [k][d]
#define WS_LOSSP  74752    // 2048: per-block loss partials (plain stores)
#define WS_TOTAL  76800    // 1
#define WS_ET     76804    // 65536: embed transposed [k][d] fp32
#define WS_KWV    142340   // 131072 floats = 262144 ushorts: per-row code (0xFFFF = masked)
#define WS_BUCKET 273412   // NSH*NEMB*capS ints: per-(shard,code) row-id lists

// RNE float->bf16 (no NaN in data), and back
__device__ __forceinline__ unsigned short f2bf(float f) {
    unsigned u = __float_as_uint(f);
    u = u + 0x7FFFu + ((u >> 16) & 1u);
    return (unsigned short)(u >> 16);
}
__device__ __forceinline__ float bf2f(unsigned short h) {
    return __uint_as_float(((unsigned)h) << 16);
}

// ---------------------------------------------------------------- prep (fused): transpose embed ->
// et[k][d]  AND  split codebook into bf16 hi/lo in 32x32x16 MFMA B-fragment order:
// frag(nt,s): lane L, elem j  <->  B[k = s*16 + (L>>5)*8 + j][n = nt*32 + (L&31)]
__global__ void vq_prep(const float* __restrict__ embed, float* __restrict__ et,
                        unsigned short* __restrict__ eh, unsigned short* __restrict__ el)
{
    int t = blockIdx.x * 256 + threadIdx.x;   // < 65536
    // transpose part: t = d*1024 + k
    int d = t >> 10;
    int k = t & (NEMB - 1);
    et[k * DIMV + d] = embed[t];
    // B-fragment part
    int j  = t & 7;
    int L  = (t >> 3) & 63;
    int s  = (t >> 9) & 3;
    int nt = t >> 11;                          // 0..31
    int db   = s * 16 + (L >> 5) * 8 + j;
    int code = nt * 32 + (L & 31);
    float e = embed[db * NEMB + code];
    unsigned short hb = f2bf(e);
    eh[t] = hb;
    el[t] = f2bf(e - bf2f(hb));
}

__global__ void vq_e2(const float* __restrict__ et, float* __restrict__ e2)
{
    int k = blockIdx.x * 256 + threadIdx.x;   // k < 1024
    const float4* ep = (const float4*)(et + k * DIMV);
    float s = 0.f;
    #pragma unroll
    for (int i = 0; i < 16; i++) {
        float4 v = ep[i];
        s = fmaf(v.x, v.x, fmaf(v.y, v.y, fmaf(v.z, v.z, fmaf(v.w, v.w, s))));
    }
    e2[k] = s;
}

// ---------------------------------------------------------------- main
// ONE m-tile (32 rows) per wave: halves A-frag + top-2 register state vs the old
// 2-tile version (VGPR 104 -> target <=102 w/ launch_bounds(256,5): >=5 waves/SIMD
// for TLP, and 2048 finer-grained blocks for a shorter straggler tail).
// Epilogue: the two half-waves sharing a row each handle 32 of its 64 dims.
__global__ __launch_bounds__(256, 5) void vq_main(
    const float* __restrict__ x, const int* __restrict__ mask,
    const unsigned short* __restrict__ eh, const unsigned short* __restrict__ el,
    const float* __restrict__ et, const float* __restrict__ e2g,
    float* __restrict__ out, unsigned short* __restrict__ kwv,
    float* __restrict__ loss_part)
{
    const int tid  = threadIdx.x;
    const int lane = tid & 63;
    const int wid  = tid >> 6;
    const int wbase = blockIdx.x * 128 + wid * 32;   // wave's first row (32 rows/wave)
    const int lm = lane & 31;    // m (A) / n (B) within tile
    const int lh = lane >> 5;    // k-half selector / epilogue dim-half

    __shared__ float lw[4];

    // ---- A fragments: xh/xl for 1 M-tile x 4 K-steps. A[m=lane&31][k=(lane>>5)*8+j]
    short8 ah[4], al[4];
    {
        const float* xr = x + (size_t)(wbase + lm) * DIMV + lh * 8;
        #pragma unroll
        for (int s = 0; s < 4; s++) {
            const float* xp = xr + s * 16;
            #pragma unroll
            for (int j = 0; j < 8; j++) {
                float f = xp[j];
                unsigned short hb = f2bf(f);
                ah[s][j] = (short)hb;
                al[s][j] = (short)f2bf(f - bf2f(hb));
            }
        }
    }

    // per-lane top-2 keys per acc-reg; key = (q<<10)|k, q = trunc(2048*(e2-2dot))
    int b1[16], b2[16];
    #pragma unroll
    for (int r = 0; r < 16; r++) { b1[r] = 0x7FFFFFFF; b2[r] = 0x7FFFFFFF; }

    const short8* ehf = (const short8*)eh;
    const short8* elf = (const short8*)el;

    for (int nt = 0; nt < 32; nt++) {
        short8 bh[4], bl[4];
        #pragma unroll
        for (int s = 0; s < 4; s++) {
            bh[s] = ehf[(nt * 4 + s) * 64 + lane];
            bl[s] = elf[(nt * 4 + s) * 64 + lane];
        }
        const int   klane = nt * 32 + lm;
        const float e2s   = e2g[klane] * 2048.0f;

        f32x16 acc;
        #pragma unroll
        for (int i = 0; i < 16; i++) acc[i] = 0.0f;

        #pragma unroll
        for (int s = 0; s < 4; s++)   // pass hh
            acc = __builtin_amdgcn_mfma_f32_32x32x16_bf16(ah[s], bh[s], acc, 0, 0, 0);
        #pragma unroll
        for (int s = 0; s < 4; s++)   // pass hl
            acc = __builtin_amdgcn_mfma_f32_32x32x16_bf16(ah[s], bl[s], acc, 0, 0, 0);
        #pragma unroll
        for (int s = 0; s < 4; s++)   // pass lh
            acc = __builtin_amdgcn_mfma_f32_32x32x16_bf16(al[s], bh[s], acc, 0, 0, 0);

        #pragma unroll
        for (int r = 0; r < 16; r++) {
            int q   = (int)fmaf(acc[r], -4096.0f, e2s);     // 2048*(e2-2dot), trunc
            int key = (int)(((unsigned)q) << 10) | klane;
            int lo = min(b1[r], key), hi = max(b1[r], key);
            b1[r] = lo; b2[r] = min(b2[r], hi);
        }
    }

    // ---- cross-lane reduction (per half-wave = 32 lanes sharing a row) ----
    int sm1 = 0x7FFFFFFF, sm2 = 0x7FFFFFFF, sc = 1;
    unsigned long long hm = (lane < 32) ? 0xFFFFFFFFull : 0xFFFFFFFF00000000ull;
    #pragma unroll
    for (int r = 0; r < 16; r++) {
        int v1 = b1[r], v2 = b2[r];
        #pragma unroll
        for (int m = 1; m <= 16; m <<= 1) {
            int o1 = __shfl_xor(v1, m, 64);
            int o2 = __shfl_xor(v2, m, 64);
            int lo = min(v1, o1), hi = max(v1, o1);
            v1 = lo;
            v2 = min(min(v2, o2), hi);
        }
        int thr = (v1 >> 10) + 41;   // window = 41/2048 ~= 0.02
        bool in1 = (b1[r] >> 10) <= thr;
        bool in2 = (b2[r] >> 10) <= thr;
        unsigned long long B1 = __ballot(in1), B2 = __ballot(in2);
        int cnt = (int)__popcll(B1 & hm) + (int)__popcll(B2 & hm);
        int w1a = __shfl(v1, 0, 64),  w2a = __shfl(v2, 0, 64),  ca = __shfl(cnt, 0, 64);
        int w1b = __shfl(v1, 32, 64), w2b = __shfl(v2, 32, 64), cb = __shfl(cnt, 32, 64);
        int r0 = (r & 3) + 8 * (r >> 2);   // row of acc reg r (hi=0 half)
        if (lane == r0)     { sm1 = w1a; sm2 = w2a; sc = ca; }
        if (lane == r0 + 4) { sm1 = w1b; sm2 = w2b; sc = cb; }
    }

    int kw = sm1 & 1023;   // meaningful on lanes 0..31 (one lane per row)

    // ---- wave-cooperative exact full scan for sc>=3 rows (rare path).
    // Only lanes 0..31 can be flagged (upper lanes still hold sc=1 init).
    {
        unsigned long long fm = __ballot(sc >= 3);
        while (fm) {
            int j = __ffsll(fm) - 1; fm &= (fm - 1);
            const float4* xr = (const float4*)(x + (size_t)(wbase + j) * DIMV);
            float4 xb[16];
            float xb2 = 0.f;
            #pragma unroll
            for (int i = 0; i < 16; i++) {
                float4 v = xr[i];                 // broadcast load (same addr all lanes)
                xb[i] = v;
                xb2 += v.x * v.x + v.y * v.y + v.z * v.z + v.w * v.w;
            }
            float bd = 3.4e38f; int bc = 0;
            for (int t = 0; t < 16; t++) {
                int c = lane + (t << 6);
                const float4* ep = (const float4*)(et + (c << 6));
                float ax = 0.f, ay = 0.f, az = 0.f, aw = 0.f;
                #pragma unroll 4
                for (int i = 0; i < 16; i++) {
                    float4 ev = ep[i];
                    ax = fmaf(xb[i].x, ev.x, ax);
                    ay = fmaf(xb[i].y, ev.y, ay);
                    az = fmaf(xb[i].z, ev.z, az);
                    aw = fmaf(xb[i].w, ev.w, aw);
                }
                float dot = (ax + ay) + (az + aw);
                float d = (xb2 - 2.0f * dot) + e2g[c];
                if (d < bd) { bd = d; bc = c; }   // ascending c: lowest idx on ties
            }
            #pragma unroll
            for (int m = 1; m < 64; m <<= 1) {    // lexicographic (dist, idx) min
                float od = __shfl_xor(bd, m, 64);
                int   oc = __shfl_xor(bc, m, 64);
                if (od < bd || (od == bd && oc < bc)) { bd = od; bc = oc; }
            }
            if (lane == j) kw = bc;
        }
    }

    // ---- broadcast per-row results from owner lane (lane&31) to both halves ----
    kw  = __shfl(kw,  lm, 64);
    sm2 = __shfl(sm2, lm, 64);
    sc  = __shfl(sc,  lm, 64);

    // ---- split-half epilogue: lane handles dims [lh*32, lh*32+32) of row wbase+lm ----
    const int row = wbase + lm;
    const bool valid = (mask[row] == 0);   // valid = ~mask

    float4 xc[8];
    {
        const float4* xp = (const float4*)(x + (size_t)row * DIMV + lh * 32);
        #pragma unroll
        for (int i = 0; i < 8; i++) xc[i] = xp[i];
    }

    if (sc == 2) {
        // exact recheck of the two candidates; half-dots combined across the lane pair
        float x2h = 0.f;
        #pragma unroll
        for (int i = 0; i < 8; i++)
            x2h += xc[i].x * xc[i].x + xc[i].y * xc[i].y + xc[i].z * xc[i].z + xc[i].w * xc[i].w;

        auto doth = [&](int k) -> float {
            const float4* ep = (const float4*)(et + (k << 6) + lh * 32);
            float ax = 0.f, ay = 0.f, az = 0.f, aw = 0.f;
            #pragma unroll
            for (int i = 0; i < 8; i++) {
                float4 ev = ep[i];
                ax = fmaf(xc[i].x, ev.x, ax);
                ay = fmaf(xc[i].y, ev.y, ay);
                az = fmaf(xc[i].z, ev.z, az);
                aw = fmaf(xc[i].w, ev.w, aw);
            }
            return (ax + ay) + (az + aw);
        };

        int k2 = sm2 & 1023;
        float p1 = x2h - 2.0f * doth(kw);
        float p2 = x2h - 2.0f * doth(k2);
        p1 += __shfl_xor(p1, 32, 64);   // combine halves (commutative -> identical on pair)
        p2 += __shfl_xor(p2, 32, 64);
        float d1 = p1 + e2g[kw];
        float d2 = p2 + e2g[k2];
        if (d2 < d1 || (d2 == d1 && k2 < kw)) kw = k2;
    }

    float sqh = 0.f;
    float4* qp = (float4*)(out + OQ + (size_t)row * DIMV + lh * 32);
    const float4* erow = (const float4*)(et + (kw << 6) + lh * 32);
    #pragma unroll
    for (int i = 0; i < 8; i++) {
        float4 xvv = xc[i];
        float4 ev  = erow[i];
        float q0 = xvv.x + (ev.x - xvv.x);
        float q1 = xvv.y + (ev.y - xvv.y);
        float q2 = xvv.z + (ev.z - xvv.z);
        float q3 = xvv.w + (ev.w - xvv.w);
        float4 q4 = {q0, q1, q2, q3};
        qp[i] = q4;
        float d0 = q0 - xvv.x, d1 = q1 - xvv.y, d2 = q2 - xvv.z, d3 = q3 - xvv.w;
        sqh += d0 * d0 + d1 * d1 + d2 * d2 + d3 * d3;
    }

    // per-row code record: ONE plain coalesced 2B store (row owner half), no atomics.
    if (lh == 0) kwv[row] = valid ? (unsigned short)kw : (unsigned short)0xFFFF;

    // per-block loss partial: each lane contributes its half-row sq; wave sum covers rows.
    float v = valid ? sqh : 0.0f;
    #pragma unroll
    for (int off = 32; off > 0; off >>= 1) v += __shfl_down(v, off, 64);
    if (lane == 0) lw[wid] = v;
    __syncthreads();
    if (tid == 0) loss_part[blockIdx.x] = (lw[0] + lw[1]) + (lw[2] + lw[3]);
}

// ---------------------------------------------------------------- bucket append (dedicated kernel).
// Cursors sharded 8x by source block: cnt[c + 1024*s]. Overflow: fire-and-forget
// fp atomics into pre-zeroed esum (rare, correct for any skew).
__global__ __launch_bounds__(256) void vq_bucket(
    const unsigned short* __restrict__ kwv, const float* __restrict__ x,
    int* __restrict__ cnt, int* __restrict__ bucket,
    float* __restrict__ esum, int capS)
{
    int row = blockIdx.x * 256 + threadIdx.x;
    unsigned short c = kwv[row];
    if (c == 0xFFFFu) return;
    int s = blockIdx.x & (NSH - 1);
    int pos = atomicAdd(&cnt[(int)c + (s << 10)], 1);
    if (pos < capS) {
        bucket[((size_t)s * NEMB + (int)c) * capS + pos] = row;
    } else {
        const float* xr = x + (size_t)row * DIMV;
        float* ep = esum + ((int)c << 6);
        #pragma unroll 8
        for (int i = 0; i < DIMV; i++) atomicAdd(ep + i, xr[i]);
    }
}

// ---------------------------------------------------------------- per-code gather-sum.
// Block per code, 8 waves; wave w owns shard w. 8-deep load ILP, fully-coalesced
// 256B row reads (d = lane). esum '+=' keeps overflow-path atomic contributions.
__global__ __launch_bounds__(512) void vq_esum(
    const float* __restrict__ x, const int* __restrict__ cnt,
    const int* __restrict__ bucket, float* __restrict__ esum, int capS)
{
    const int tid  = threadIdx.x;
    const int lane = tid & 63;
    const int wid  = tid >> 6;      // 0..7 = shard
    const int c    = blockIdx.x;
    const int n    = min(cnt[c + (wid << 10)], capS);
    const int* bp  = bucket + ((size_t)wid * NEMB + c) * capS;
    __shared__ float part[8][64];

    float acc = 0.f;
    for (int i = 0; i < n; i += 8) {
        float tmp[8];
        if (i + 8 <= n) {
            // bulk: two 16B broadcast loads of 8 contiguous row-ids (capS is 8-aligned)
            int4 a = *(const int4*)(bp + i);
            int4 b = *(const int4*)(bp + i + 4);
            tmp[0] = x[(size_t)a.x * DIMV + lane];
            tmp[1] = x[(size_t)a.y * DIMV + lane];
            tmp[2] = x[(size_t)a.z * DIMV + lane];
            tmp[3] = x[(size_t)a.w * DIMV + lane];
            tmp[4] = x[(size_t)b.x * DIMV + lane];
            tmp[5] = x[(size_t)b.y * DIMV + lane];
            tmp[6] = x[(size_t)b.z * DIMV + lane];
            tmp[7] = x[(size_t)b.w * DIMV + lane];
        } else {
            #pragma unroll
            for (int k = 0; k < 8; k++) {
                int idx = i + k;
                tmp[k] = (idx < n) ? x[(size_t)bp[idx] * DIMV + lane] : 0.f;
            }
        }
        acc += ((tmp[0] + tmp[1]) + (tmp[2] + tmp[3]))
             + ((tmp[4] + tmp[5]) + (tmp[6] + tmp[7]));
    }

    part[wid][lane] = acc;
    __syncthreads();
    if (tid < 64) {
        float s = 0.f;
        #pragma unroll
        for (int w = 0; w < 8; w++) s += part[w][lane];
        esum[(c << 6) + lane] += s;   // += keeps overflow atomics (esum pre-zeroed)
    }
}

// ---------------------------------------------------------------- finalize A
// counts = sum of 8 shard cursors; loss = tree-reduce of 2048 per-block partials.
__global__ __launch_bounds__(1024) void vq_finalA(
    const float* __restrict__ cluster_size, const int* __restrict__ cnt,
    const float* __restrict__ loss_part, float* __restrict__ out,
    float* __restrict__ total_ws)
{
    __shared__ float s1[1024];
    __shared__ float s2[1024];
    __shared__ float s3[1024];
    int k = threadIdx.x;
    int ci = 0;
    #pragma unroll
    for (int s = 0; s < NSH; s++) ci += cnt[k + (s << 10)];
    float c   = (float)ci;
    float ncs = cluster_size[k] * DECAYF + OMDF * c;
    out[ONC + k] = ncs;
    s1[k] = ncs; s2[k] = c; s3[k] = loss_part[k] + loss_part[k + 1024];
    __syncthreads();
    for (int off = 512; off > 0; off >>= 1) {
        if (k < off) { s1[k] += s1[k + off]; s2[k] += s2[k + off]; s3[k] += s3[k + off]; }
        __syncthreads();
    }
    if (k == 0) {
        total_ws[0] = s1[0];
        out[OL] = s3[0] / (s2[0] * (float)DIMV);
    }
}

// ---------------------------------------------------------------- finalize B (esum is k-major)
__global__ void vq_finalB(const float* __restrict__ embed_avg,
                          const float* __restrict__ esum,
                          float* __restrict__ out,
                          const float* __restrict__ total_ws)
{
    int idx = blockIdx.x * 256 + threadIdx.x;  // < 65536, idx = d*1024 + k
    int k = idx & (NEMB - 1);
    int d = idx >> 10;
    float avg = embed_avg[idx] * DECAYF + OMDF * esum[(k << 6) + d];
    out[OA + idx] = avg;
    float ncs   = out[ONC + k];
    float total = *total_ws;
    float sm = (ncs + EPSF) / (total + (float)NEMB * EPSF) * total;
    out[OE + idx] = avg / sm;
}

// ---------------------------------------------------------------- launcher
extern "C" void kernel_launch(void* const* d_in, const int* in_sizes, int n_in,
                              void* d_out, int out_size, void* d_ws, size_t ws_size,
                              hipStream_t stream)
{
    const float* x            = (const float*)d_in[0];
    const int*   mask         = (const int*)d_in[1];
    const float* embed        = (const float*)d_in[2];
    const float* cluster_size = (const float*)d_in[3];
    const float* embed_avg    = (const float*)d_in[4];
    float* out = (float*)d_out;
    float* ws  = (float*)d_ws;

    unsigned short* eh     = (unsigned short*)(out + OEH);
    unsigned short* el     = (unsigned short*)(out + OEL);
    unsigned short* kwv    = (unsigned short*)(ws + WS_KWV);
    int*            cnt    = (int*)(ws + WS_CNT);
    int*            bucket = (int*)(ws + WS_BUCKET);

    // per-shard bucket capacity from available workspace (8-aligned for int4 reads);
    // capS == 0 -> all rows take the overflow-atomic path (slow but correct).
    int capS = 0;
    size_t avail = ws_size / sizeof(float);
    if (avail > (size_t)WS_BUCKET) {
        size_t per = (avail - (size_t)WS_BUCKET) / ((size_t)NEMB * NSH);
        if (per > 768) per = 768;
        capS = (int)per & ~7;
    }

    // zero cursors + esum (loss partials are fully overwritten by vq_main)
    hipMemsetAsync(ws + WS_CNT, 0, (size_t)(WS_LOSSP - WS_CNT) * sizeof(float), stream);

    vq_prep<<<65536 / 256, 256, 0, stream>>>(embed, ws + WS_ET, eh, el);
    vq_e2<<<NEMB / 256, 256, 0, stream>>>(ws + WS_ET, ws + WS_E2);
    vq_main<<<NROWS / 128, 256, 0, stream>>>(x, mask, eh, el, ws + WS_ET, ws + WS_E2,
                                             out, kwv, ws + WS_LOSSP);
    vq_bucket<<<NROWS / 256, 256, 0, stream>>>(kwv, x, cnt, bucket, ws + WS_ESUM, capS);
    vq_esum<<<NEMB, 512, 0, stream>>>(x, cnt, bucket, ws + WS_ESUM, capS);
    vq_finalA<<<1, 1024, 0, stream>>>(cluster_size, cnt, ws + WS_LOSSP,
                                      out, ws + WS_TOTAL);
    vq_finalB<<<65536 / 256, 256, 0, stream>>>(embed_avg, ws + WS_ESUM, out, ws + WS_TOTAL);
}

// Round 8
// 341.424 us; speedup vs baseline: 1.4752x; 1.4752x over previous
//
#include <hip/hip_runtime.h>

typedef short short8 __attribute__((ext_vector_type(8)));
typedef float f32x16 __attribute__((ext_vector_type(16)));

// Problem constants
#define DIMV   64
#define NEMB   1024
#define NROWS  262144          // B*T = 2048*128
#define DECAYF 0.99f
#define OMDF   0.01f
#define EPSF   1e-5f
#define NSH    8               // bucket cursor shards (parallelize atomic drain)

// d_out layout (floats): quantize | loss | new_embed | new_cluster_size | new_embed_avg
#define OQ   0
#define OL   16777216
#define OE   16777217
#define ONC  16842753
#define OA   16843777
// EH/EL (bf16 split codebook, MFMA-B-fragment order) live in the d_out tail:
// written by vq_prep, read by vq_main, then overwritten by finalA/finalB.
#define OEH  16777216
#define OEL  (16777216 + 32768)

// d_ws layout (floats)
#define WS_E2     0        // 1024: ||e_k||^2
#define WS_CNT    1024     // 8192 ints: sharded cursors cnt[c + 1024*s]
#define WS_ESUM   9216     // 65536: embed_sum, K-MAJOR: [k][d]
#define WS_LOSSP  74752    // 2048: per-block loss partials (plain stores)
#define WS_TOTAL  76800    // 1
#define WS_ET     76804    // 65536: embed transposed [k][d] fp32
#define WS_KWV    142340   // 131072 floats = 262144 ushorts: per-row code (0xFFFF = masked)
#define WS_BUCKET 273412   // NSH*NEMB*capS ints: per-(shard,code) row-id lists

// RNE float->bf16 (no NaN in data), and back
__device__ __forceinline__ unsigned short f2bf(float f) {
    unsigned u = __float_as_uint(f);
    u = u + 0x7FFFu + ((u >> 16) & 1u);
    return (unsigned short)(u >> 16);
}
__device__ __forceinline__ float bf2f(unsigned short h) {
    return __uint_as_float(((unsigned)h) << 16);
}

// ---------------------------------------------------------------- prep (fused): transpose embed ->
// et[k][d]  AND  split codebook into bf16 hi/lo in 32x32x16 MFMA B-fragment order:
// frag(nt,s): lane L, elem j  <->  B[k = s*16 + (L>>5)*8 + j][n = nt*32 + (L&31)]
__global__ void vq_prep(const float* __restrict__ embed, float* __restrict__ et,
                        unsigned short* __restrict__ eh, unsigned short* __restrict__ el)
{
    int t = blockIdx.x * 256 + threadIdx.x;   // < 65536
    // transpose part: t = d*1024 + k
    int d = t >> 10;
    int k = t & (NEMB - 1);
    et[k * DIMV + d] = embed[t];
    // B-fragment part
    int j  = t & 7;
    int L  = (t >> 3) & 63;
    int s  = (t >> 9) & 3;
    int nt = t >> 11;                          // 0..31
    int db   = s * 16 + (L >> 5) * 8 + j;
    int code = nt * 32 + (L & 31);
    float e = embed[db * NEMB + code];
    unsigned short hb = f2bf(e);
    eh[t] = hb;
    el[t] = f2bf(e - bf2f(hb));
}

__global__ void vq_e2(const float* __restrict__ et, float* __restrict__ e2)
{
    int k = blockIdx.x * 256 + threadIdx.x;   // k < 1024
    const float4* ep = (const float4*)(et + k * DIMV);
    float s = 0.f;
    #pragma unroll
    for (int i = 0; i < 16; i++) {
        float4 v = ep[i];
        s = fmaf(v.x, v.x, fmaf(v.y, v.y, fmaf(v.z, v.z, fmaf(v.w, v.w, s))));
    }
    e2[k] = s;
}

// ---------------------------------------------------------------- main
// ONE m-tile (32 rows) per wave. Round 7's launch_bounds(256,5) (VGPR cap 102)
// forced a spill-to-scratch (VGPR=48, 3x memory traffic, +65% time). (256,4)
// caps at 128: natural footprint ~90-105 fits WITHOUT spill, and <=102 actual
// still yields 5 waves/SIMD occupancy.
__global__ __launch_bounds__(256, 4) void vq_main(
    const float* __restrict__ x, const int* __restrict__ mask,
    const unsigned short* __restrict__ eh, const unsigned short* __restrict__ el,
    const float* __restrict__ et, const float* __restrict__ e2g,
    float* __restrict__ out, unsigned short* __restrict__ kwv,
    float* __restrict__ loss_part)
{
    const int tid  = threadIdx.x;
    const int lane = tid & 63;
    const int wid  = tid >> 6;
    const int wbase = blockIdx.x * 128 + wid * 32;   // wave's first row (32 rows/wave)
    const int lm = lane & 31;    // m (A) / n (B) within tile
    const int lh = lane >> 5;    // k-half selector / epilogue dim-half

    __shared__ float lw[4];

    // ---- A fragments: xh/xl for 1 M-tile x 4 K-steps. A[m=lane&31][k=(lane>>5)*8+j]
    short8 ah[4], al[4];
    {
        const float* xr = x + (size_t)(wbase + lm) * DIMV + lh * 8;
        #pragma unroll
        for (int s = 0; s < 4; s++) {
            const float* xp = xr + s * 16;
            #pragma unroll
            for (int j = 0; j < 8; j++) {
                float f = xp[j];
                unsigned short hb = f2bf(f);
                ah[s][j] = (short)hb;
                al[s][j] = (short)f2bf(f - bf2f(hb));
            }
        }
    }

    // per-lane top-2 keys per acc-reg; key = (q<<10)|k, q = trunc(2048*(e2-2dot))
    int b1[16], b2[16];
    #pragma unroll
    for (int r = 0; r < 16; r++) { b1[r] = 0x7FFFFFFF; b2[r] = 0x7FFFFFFF; }

    const short8* ehf = (const short8*)eh;
    const short8* elf = (const short8*)el;

    for (int nt = 0; nt < 32; nt++) {
        short8 bh[4], bl[4];
        #pragma unroll
        for (int s = 0; s < 4; s++) {
            bh[s] = ehf[(nt * 4 + s) * 64 + lane];
            bl[s] = elf[(nt * 4 + s) * 64 + lane];
        }
        const int   klane = nt * 32 + lm;
        const float e2s   = e2g[klane] * 2048.0f;

        f32x16 acc;
        #pragma unroll
        for (int i = 0; i < 16; i++) acc[i] = 0.0f;

        #pragma unroll
        for (int s = 0; s < 4; s++)   // pass hh
            acc = __builtin_amdgcn_mfma_f32_32x32x16_bf16(ah[s], bh[s], acc, 0, 0, 0);
        #pragma unroll
        for (int s = 0; s < 4; s++)   // pass hl
            acc = __builtin_amdgcn_mfma_f32_32x32x16_bf16(ah[s], bl[s], acc, 0, 0, 0);
        #pragma unroll
        for (int s = 0; s < 4; s++)   // pass lh
            acc = __builtin_amdgcn_mfma_f32_32x32x16_bf16(al[s], bh[s], acc, 0, 0, 0);

        #pragma unroll
        for (int r = 0; r < 16; r++) {
            int q   = (int)fmaf(acc[r], -4096.0f, e2s);     // 2048*(e2-2dot), trunc
            int key = (int)(((unsigned)q) << 10) | klane;
            int lo = min(b1[r], key), hi = max(b1[r], key);
            b1[r] = lo; b2[r] = min(b2[r], hi);
        }
    }

    // ---- cross-lane reduction (per half-wave = 32 lanes sharing a row) ----
    int sm1 = 0x7FFFFFFF, sm2 = 0x7FFFFFFF, sc = 1;
    unsigned long long hm = (lane < 32) ? 0xFFFFFFFFull : 0xFFFFFFFF00000000ull;
    #pragma unroll
    for (int r = 0; r < 16; r++) {
        int v1 = b1[r], v2 = b2[r];
        #pragma unroll
        for (int m = 1; m <= 16; m <<= 1) {
            int o1 = __shfl_xor(v1, m, 64);
            int o2 = __shfl_xor(v2, m, 64);
            int lo = min(v1, o1), hi = max(v1, o1);
            v1 = lo;
            v2 = min(min(v2, o2), hi);
        }
        int thr = (v1 >> 10) + 41;   // window = 41/2048 ~= 0.02
        bool in1 = (b1[r] >> 10) <= thr;
        bool in2 = (b2[r] >> 10) <= thr;
        unsigned long long B1 = __ballot(in1), B2 = __ballot(in2);
        int cnt = (int)__popcll(B1 & hm) + (int)__popcll(B2 & hm);
        int w1a = __shfl(v1, 0, 64),  w2a = __shfl(v2, 0, 64),  ca = __shfl(cnt, 0, 64);
        int w1b = __shfl(v1, 32, 64), w2b = __shfl(v2, 32, 64), cb = __shfl(cnt, 32, 64);
        int r0 = (r & 3) + 8 * (r >> 2);   // row of acc reg r (hi=0 half)
        if (lane == r0)     { sm1 = w1a; sm2 = w2a; sc = ca; }
        if (lane == r0 + 4) { sm1 = w1b; sm2 = w2b; sc = cb; }
    }

    int kw = sm1 & 1023;   // meaningful on lanes 0..31 (one lane per row)

    // ---- wave-cooperative exact full scan for sc>=3 rows (rare path).
    // Only lanes 0..31 can be flagged (upper lanes still hold sc=1 init).
    {
        unsigned long long fm = __ballot(sc >= 3);
        while (fm) {
            int j = __ffsll(fm) - 1; fm &= (fm - 1);
            const float4* xr = (const float4*)(x + (size_t)(wbase + j) * DIMV);
            float4 xb[16];
            float xb2 = 0.f;
            #pragma unroll
            for (int i = 0; i < 16; i++) {
                float4 v = xr[i];                 // broadcast load (same addr all lanes)
                xb[i] = v;
                xb2 += v.x * v.x + v.y * v.y + v.z * v.z + v.w * v.w;
            }
            float bd = 3.4e38f; int bc = 0;
            for (int t = 0; t < 16; t++) {
                int c = lane + (t << 6);
                const float4* ep = (const float4*)(et + (c << 6));
                float ax = 0.f, ay = 0.f, az = 0.f, aw = 0.f;
                #pragma unroll 4
                for (int i = 0; i < 16; i++) {
                    float4 ev = ep[i];
                    ax = fmaf(xb[i].x, ev.x, ax);
                    ay = fmaf(xb[i].y, ev.y, ay);
                    az = fmaf(xb[i].z, ev.z, az);
                    aw = fmaf(xb[i].w, ev.w, aw);
                }
                float dot = (ax + ay) + (az + aw);
                float d = (xb2 - 2.0f * dot) + e2g[c];
                if (d < bd) { bd = d; bc = c; }   // ascending c: lowest idx on ties
            }
            #pragma unroll
            for (int m = 1; m < 64; m <<= 1) {    // lexicographic (dist, idx) min
                float od = __shfl_xor(bd, m, 64);
                int   oc = __shfl_xor(bc, m, 64);
                if (od < bd || (od == bd && oc < bc)) { bd = od; bc = oc; }
            }
            if (lane == j) kw = bc;
        }
    }

    // ---- broadcast per-row results from owner lane (lane&31) to both halves ----
    kw  = __shfl(kw,  lm, 64);
    sm2 = __shfl(sm2, lm, 64);
    sc  = __shfl(sc,  lm, 64);

    // ---- split-half epilogue: lane handles dims [lh*32, lh*32+32) of row wbase+lm ----
    const int row = wbase + lm;
    const bool valid = (mask[row] == 0);   // valid = ~mask

    float4 xc[8];
    {
        const float4* xp = (const float4*)(x + (size_t)row * DIMV + lh * 32);
        #pragma unroll
        for (int i = 0; i < 8; i++) xc[i] = xp[i];
    }

    if (sc == 2) {
        // exact recheck of the two candidates; half-dots combined across the lane pair
        float x2h = 0.f;
        #pragma unroll
        for (int i = 0; i < 8; i++)
            x2h += xc[i].x * xc[i].x + xc[i].y * xc[i].y + xc[i].z * xc[i].z + xc[i].w * xc[i].w;

        auto doth = [&](int k) -> float {
            const float4* ep = (const float4*)(et + (k << 6) + lh * 32);
            float ax = 0.f, ay = 0.f, az = 0.f, aw = 0.f;
            #pragma unroll
            for (int i = 0; i < 8; i++) {
                float4 ev = ep[i];
                ax = fmaf(xc[i].x, ev.x, ax);
                ay = fmaf(xc[i].y, ev.y, ay);
                az = fmaf(xc[i].z, ev.z, az);
                aw = fmaf(xc[i].w, ev.w, aw);
            }
            return (ax + ay) + (az + aw);
        };

        int k2 = sm2 & 1023;
        float p1 = x2h - 2.0f * doth(kw);
        float p2 = x2h - 2.0f * doth(k2);
        p1 += __shfl_xor(p1, 32, 64);   // combine halves (commutative -> identical on pair)
        p2 += __shfl_xor(p2, 32, 64);
        float d1 = p1 + e2g[kw];
        float d2 = p2 + e2g[k2];
        if (d2 < d1 || (d2 == d1 && k2 < kw)) kw = k2;
    }

    float sqh = 0.f;
    float4* qp = (float4*)(out + OQ + (size_t)row * DIMV + lh * 32);
    const float4* erow = (const float4*)(et + (kw << 6) + lh * 32);
    #pragma unroll
    for (int i = 0; i < 8; i++) {
        float4 xvv = xc[i];
        float4 ev  = erow[i];
        float q0 = xvv.x + (ev.x - xvv.x);
        float q1 = xvv.y + (ev.y - xvv.y);
        float q2 = xvv.z + (ev.z - xvv.z);
        float q3 = xvv.w + (ev.w - xvv.w);
        float4 q4 = {q0, q1, q2, q3};
        qp[i] = q4;
        float d0 = q0 - xvv.x, d1 = q1 - xvv.y, d2 = q2 - xvv.z, d3 = q3 - xvv.w;
        sqh += d0 * d0 + d1 * d1 + d2 * d2 + d3 * d3;
    }

    // per-row code record: ONE plain coalesced 2B store (row owner half), no atomics.
    if (lh == 0) kwv[row] = valid ? (unsigned short)kw : (unsigned short)0xFFFF;

    // per-block loss partial: each lane contributes its half-row sq; wave sum covers rows.
    float v = valid ? sqh : 0.0f;
    #pragma unroll
    for (int off = 32; off > 0; off >>= 1) v += __shfl_down(v, off, 64);
    if (lane == 0) lw[wid] = v;
    __syncthreads();
    if (tid == 0) loss_part[blockIdx.x] = (lw[0] + lw[1]) + (lw[2] + lw[3]);
}

// ---------------------------------------------------------------- bucket append (dedicated kernel).
// Cursors sharded 8x by source block: cnt[c + 1024*s]. Overflow: fire-and-forget
// fp atomics into pre-zeroed esum (rare, correct for any skew).
__global__ __launch_bounds__(256) void vq_bucket(
    const unsigned short* __restrict__ kwv, const float* __restrict__ x,
    int* __restrict__ cnt, int* __restrict__ bucket,
    float* __restrict__ esum, int capS)
{
    int row = blockIdx.x * 256 + threadIdx.x;
    unsigned short c = kwv[row];
    if (c == 0xFFFFu) return;
    int s = blockIdx.x & (NSH - 1);
    int pos = atomicAdd(&cnt[(int)c + (s << 10)], 1);
    if (pos < capS) {
        bucket[((size_t)s * NEMB + (int)c) * capS + pos] = row;
    } else {
        const float* xr = x + (size_t)row * DIMV;
        float* ep = esum + ((int)c << 6);
        #pragma unroll 8
        for (int i = 0; i < DIMV; i++) atomicAdd(ep + i, xr[i]);
    }
}

// ---------------------------------------------------------------- per-code gather-sum.
// Block per code, 8 waves; wave w owns shard w. 8-deep load ILP, fully-coalesced
// 256B row reads (d = lane). esum '+=' keeps overflow-path atomic contributions.
__global__ __launch_bounds__(512) void vq_esum(
    const float* __restrict__ x, const int* __restrict__ cnt,
    const int* __restrict__ bucket, float* __restrict__ esum, int capS)
{
    const int tid  = threadIdx.x;
    const int lane = tid & 63;
    const int wid  = tid >> 6;      // 0..7 = shard
    const int c    = blockIdx.x;
    const int n    = min(cnt[c + (wid << 10)], capS);
    const int* bp  = bucket + ((size_t)wid * NEMB + c) * capS;
    __shared__ float part[8][64];

    float acc = 0.f;
    for (int i = 0; i < n; i += 8) {
        float tmp[8];
        if (i + 8 <= n) {
            // bulk: two 16B broadcast loads of 8 contiguous row-ids (capS is 8-aligned)
            int4 a = *(const int4*)(bp + i);
            int4 b = *(const int4*)(bp + i + 4);
            tmp[0] = x[(size_t)a.x * DIMV + lane];
            tmp[1] = x[(size_t)a.y * DIMV + lane];
            tmp[2] = x[(size_t)a.z * DIMV + lane];
            tmp[3] = x[(size_t)a.w * DIMV + lane];
            tmp[4] = x[(size_t)b.x * DIMV + lane];
            tmp[5] = x[(size_t)b.y * DIMV + lane];
            tmp[6] = x[(size_t)b.z * DIMV + lane];
            tmp[7] = x[(size_t)b.w * DIMV + lane];
        } else {
            #pragma unroll
            for (int k = 0; k < 8; k++) {
                int idx = i + k;
                tmp[k] = (idx < n) ? x[(size_t)bp[idx] * DIMV + lane] : 0.f;
            }
        }
        acc += ((tmp[0] + tmp[1]) + (tmp[2] + tmp[3]))
             + ((tmp[4] + tmp[5]) + (tmp[6] + tmp[7]));
    }

    part[wid][lane] = acc;
    __syncthreads();
    if (tid < 64) {
        float s = 0.f;
        #pragma unroll
        for (int w = 0; w < 8; w++) s += part[w][lane];
        esum[(c << 6) + lane] += s;   // += keeps overflow atomics (esum pre-zeroed)
    }
}

// ---------------------------------------------------------------- finalize A
// counts = sum of 8 shard cursors; loss = tree-reduce of 2048 per-block partials.
__global__ __launch_bounds__(1024) void vq_finalA(
    const float* __restrict__ cluster_size, const int* __restrict__ cnt,
    const float* __restrict__ loss_part, float* __restrict__ out,
    float* __restrict__ total_ws)
{
    __shared__ float s1[1024];
    __shared__ float s2[1024];
    __shared__ float s3[1024];
    int k = threadIdx.x;
    int ci = 0;
    #pragma unroll
    for (int s = 0; s < NSH; s++) ci += cnt[k + (s << 10)];
    float c   = (float)ci;
    float ncs = cluster_size[k] * DECAYF + OMDF * c;
    out[ONC + k] = ncs;
    s1[k] = ncs; s2[k] = c; s3[k] = loss_part[k] + loss_part[k + 1024];
    __syncthreads();
    for (int off = 512; off > 0; off >>= 1) {
        if (k < off) { s1[k] += s1[k + off]; s2[k] += s2[k + off]; s3[k] += s3[k + off]; }
        __syncthreads();
    }
    if (k == 0) {
        total_ws[0] = s1[0];
        out[OL] = s3[0] / (s2[0] * (float)DIMV);
    }
}

// ---------------------------------------------------------------- finalize B (esum is k-major)
__global__ void vq_finalB(const float* __restrict__ embed_avg,
                          const float* __restrict__ esum,
                          float* __restrict__ out,
                          const float* __restrict__ total_ws)
{
    int idx = blockIdx.x * 256 + threadIdx.x;  // < 65536, idx = d*1024 + k
    int k = idx & (NEMB - 1);
    int d = idx >> 10;
    float avg = embed_avg[idx] * DECAYF + OMDF * esum[(k << 6) + d];
    out[OA + idx] = avg;
    float ncs   = out[ONC + k];
    float total = *total_ws;
    float sm = (ncs + EPSF) / (total + (float)NEMB * EPSF) * total;
    out[OE + idx] = avg / sm;
}

// ---------------------------------------------------------------- launcher
extern "C" void kernel_launch(void* const* d_in, const int* in_sizes, int n_in,
                              void* d_out, int out_size, void* d_ws, size_t ws_size,
                              hipStream_t stream)
{
    const float* x            = (const float*)d_in[0];
    const int*   mask         = (const int*)d_in[1];
    const float* embed        = (const float*)d_in[2];
    const float* cluster_size = (const float*)d_in[3];
    const float* embed_avg    = (const float*)d_in[4];
    float* out = (float*)d_out;
    float* ws  = (float*)d_ws;

    unsigned short* eh     = (unsigned short*)(out + OEH);
    unsigned short* el     = (unsigned short*)(out + OEL);
    unsigned short* kwv    = (unsigned short*)(ws + WS_KWV);
    int*            cnt    = (int*)(ws + WS_CNT);
    int*            bucket = (int*)(ws + WS_BUCKET);

    // per-shard bucket capacity from available workspace (8-aligned for int4 reads);
    // capS == 0 -> all rows take the overflow-atomic path (slow but correct).
    int capS = 0;
    size_t avail = ws_size / sizeof(float);
    if (avail > (size_t)WS_BUCKET) {
        size_t per = (avail - (size_t)WS_BUCKET) / ((size_t)NEMB * NSH);
        if (per > 768) per = 768;
        capS = (int)per & ~7;
    }

    // zero cursors + esum (loss partials are fully overwritten by vq_main)
    hipMemsetAsync(ws + WS_CNT, 0, (size_t)(WS_LOSSP - WS_CNT) * sizeof(float), stream);

    vq_prep<<<65536 / 256, 256, 0, stream>>>(embed, ws + WS_ET, eh, el);
    vq_e2<<<NEMB / 256, 256, 0, stream>>>(ws + WS_ET, ws + WS_E2);
    vq_main<<<NROWS / 128, 256, 0, stream>>>(x, mask, eh, el, ws + WS_ET, ws + WS_E2,
                                             out, kwv, ws + WS_LOSSP);
    vq_bucket<<<NROWS / 256, 256, 0, stream>>>(kwv, x, cnt, bucket, ws + WS_ESUM, capS);
    vq_esum<<<NEMB, 512, 0, stream>>>(x, cnt, bucket, ws + WS_ESUM, capS);
    vq_finalA<<<1, 1024, 0, stream>>>(cluster_size, cnt, ws + WS_LOSSP,
                                      out, ws + WS_TOTAL);
    vq_finalB<<<65536 / 256, 256, 0, stream>>>(embed_avg, ws + WS_ESUM, out, ws + WS_TOTAL);
}

// Round 9
// 339.044 us; speedup vs baseline: 1.4856x; 1.0070x over previous
//
#include <hip/hip_runtime.h>

typedef short short8 __attribute__((ext_vector_type(8)));
typedef float f32x16 __attribute__((ext_vector_type(16)));

// Problem constants
#define DIMV   64
#define NEMB   1024
#define NROWS  262144          // B*T = 2048*128
#define DECAYF 0.99f
#define OMDF   0.01f
#define EPSF   1e-5f
#define NSH    8               // bucket cursor shards (parallelize atomic drain)

// d_out layout (floats): quantize | loss | new_embed | new_cluster_size | new_embed_avg
#define OQ   0
#define OL   16777216
#define OE   16777217
#define ONC  16842753
#define OA   16843777
// EH/EL (bf16 split codebook, MFMA-B-fragment order) live in the d_out tail:
// written by vq_prep, read by vq_main, then overwritten by finalA/finalB.
#define OEH  16777216
#define OEL  (16777216 + 32768)

// d_ws layout (floats)
#define WS_E2     0        // 1024: ||e_k||^2
#define WS_CNT    1024     // 8192 ints: sharded cursors cnt[c + 1024*s]
#define WS_ESUM   9216     // 65536: embed_sum, K-MAJOR: [k][d]
#define WS_LOSSP  74752    // 2048: per-block loss partials (plain stores)
#define WS_TOTAL  76800    // 1
#define WS_ET     76804    // 65536: embed transposed [k][d] fp32
#define WS_KWV    142340   // 131072 floats = 262144 ushorts: per-row code (0xFFFF = masked)
#define WS_BUCKET 273412   // NSH*NEMB*capS ints: per-(shard,code) row-id lists

// RNE float->bf16 (no NaN in data), and back
__device__ __forceinline__ unsigned short f2bf(float f) {
    unsigned u = __float_as_uint(f);
    u = u + 0x7FFFu + ((u >> 16) & 1u);
    return (unsigned short)(u >> 16);
}
__device__ __forceinline__ float bf2f(unsigned short h) {
    return __uint_as_float(((unsigned)h) << 16);
}

// async global -> LDS, 16 B per lane. lptr must be WAVE-UNIFORM; HW appends lane*16.
__device__ __forceinline__ void gload_lds16(const void* g, void* l) {
    __builtin_amdgcn_global_load_lds(
        (const __attribute__((address_space(1))) unsigned int*)g,
        (__attribute__((address_space(3))) unsigned int*)l, 16, 0, 0);
}

// ---------------------------------------------------------------- prep (fused): transpose embed ->
// et[k][d]  AND  split codebook into bf16 hi/lo in 32x32x16 MFMA B-fragment order:
// frag(nt,s): lane L, elem j  <->  B[k = s*16 + (L>>5)*8 + j][n = nt*32 + (L&31)]
__global__ void vq_prep(const float* __restrict__ embed, float* __restrict__ et,
                        unsigned short* __restrict__ eh, unsigned short* __restrict__ el)
{
    int t = blockIdx.x * 256 + threadIdx.x;   // < 65536
    // transpose part: t = d*1024 + k
    int d = t >> 10;
    int k = t & (NEMB - 1);
    et[k * DIMV + d] = embed[t];
    // B-fragment part
    int j  = t & 7;
    int L  = (t >> 3) & 63;
    int s  = (t >> 9) & 3;
    int nt = t >> 11;                          // 0..31
    int db   = s * 16 + (L >> 5) * 8 + j;
    int code = nt * 32 + (L & 31);
    float e = embed[db * NEMB + code];
    unsigned short hb = f2bf(e);
    eh[t] = hb;
    el[t] = f2bf(e - bf2f(hb));
}

__global__ void vq_e2(const float* __restrict__ et, float* __restrict__ e2)
{
    int k = blockIdx.x * 256 + threadIdx.x;   // k < 1024
    const float4* ep = (const float4*)(et + k * DIMV);
    float s = 0.f;
    #pragma unroll
    for (int i = 0; i < 16; i++) {
        float4 v = ep[i];
        s = fmaf(v.x, v.x, fmaf(v.y, v.y, fmaf(v.z, v.z, fmaf(v.w, v.w, s))));
    }
    e2[k] = s;
}

// ---------------------------------------------------------------- main
// ONE m-tile (32 rows) per wave, VGPR=64 (8 waves/SIMD). B-fragments (eh/el) are
// now double-buffered in LDS via global_load_lds: one 8 KB tile staged per BLOCK
// per nt instead of 4 identical per-wave global-load sets -> 4x less L2 traffic
// (2.1 GB -> 0.5 GB) and zero per-load 64-bit address VALU (ds offsets fold).
__global__ __launch_bounds__(256, 4) void vq_main(
    const float* __restrict__ x, const int* __restrict__ mask,
    const unsigned short* __restrict__ eh, const unsigned short* __restrict__ el,
    const float* __restrict__ et, const float* __restrict__ e2g,
    float* __restrict__ out, unsigned short* __restrict__ kwv,
    float* __restrict__ loss_part)
{
    const int tid  = threadIdx.x;
    const int lane = tid & 63;
    const int wid  = tid >> 6;
    const int wbase = blockIdx.x * 128 + wid * 32;   // wave's first row (32 rows/wave)
    const int lm = lane & 31;    // m (A) / n (B) within tile
    const int lh = lane >> 5;    // k-half selector / epilogue dim-half

    __shared__ short8 sb[2][8][64];   // [buf][bh:0..3 | bl:4..7][lane] = 16 KB dbuf
    __shared__ float lw[4];

    // ---- A fragments: xh/xl for 1 M-tile x 4 K-steps. A[m=lane&31][k=(lane>>5)*8+j]
    short8 ah[4], al[4];
    {
        const float* xr = x + (size_t)(wbase + lm) * DIMV + lh * 8;
        #pragma unroll
        for (int s = 0; s < 4; s++) {
            const float* xp = xr + s * 16;
            #pragma unroll
            for (int j = 0; j < 8; j++) {
                float f = xp[j];
                unsigned short hb = f2bf(f);
                ah[s][j] = (short)hb;
                al[s][j] = (short)f2bf(f - bf2f(hb));
            }
        }
    }

    // per-lane top-2 keys per acc-reg; key = (q<<10)|k, q = trunc(2048*(e2-2dot))
    int b1[16], b2[16];
    #pragma unroll
    for (int r = 0; r < 16; r++) { b1[r] = 0x7FFFFFFF; b2[r] = 0x7FFFFFFF; }

    const short8* ehf = (const short8*)eh;   // element t = frag elem (nt*256 + s*64 + lane)
    const short8* elf = (const short8*)el;

    // prologue: stage tile nt=0 into buf 0 (each wave stages its quarter: s = wid)
    gload_lds16(ehf + tid, &sb[0][wid][0]);
    gload_lds16(elf + tid, &sb[0][4 + wid][0]);

    int cur = 0;
    for (int nt = 0; nt < 32; nt++) {
        // barrier: (a) this block's stage of buf[cur] landed (syncthreads drains each
        // wave's vmcnt), (b) everyone's ds_reads of buf[cur^1] from nt-1 are done.
        __syncthreads();
        if (nt < 31) {   // stage next tile into the buffer just freed
            gload_lds16(ehf + (nt + 1) * 256 + tid, &sb[cur ^ 1][wid][0]);
            gload_lds16(elf + (nt + 1) * 256 + tid, &sb[cur ^ 1][4 + wid][0]);
        }

        short8 bh[4], bl[4];
        #pragma unroll
        for (int s = 0; s < 4; s++) {
            bh[s] = sb[cur][s][lane];        // ds_read_b128, compile-time offsets
            bl[s] = sb[cur][4 + s][lane];
        }
        const int   klane = nt * 32 + lm;
        const float e2s   = e2g[klane] * 2048.0f;

        f32x16 acc;
        #pragma unroll
        for (int i = 0; i < 16; i++) acc[i] = 0.0f;

        #pragma unroll
        for (int s = 0; s < 4; s++)   // pass hh
            acc = __builtin_amdgcn_mfma_f32_32x32x16_bf16(ah[s], bh[s], acc, 0, 0, 0);
        #pragma unroll
        for (int s = 0; s < 4; s++)   // pass hl
            acc = __builtin_amdgcn_mfma_f32_32x32x16_bf16(ah[s], bl[s], acc, 0, 0, 0);
        #pragma unroll
        for (int s = 0; s < 4; s++)   // pass lh
            acc = __builtin_amdgcn_mfma_f32_32x32x16_bf16(al[s], bh[s], acc, 0, 0, 0);

        #pragma unroll
        for (int r = 0; r < 16; r++) {
            int q   = (int)fmaf(acc[r], -4096.0f, e2s);     // 2048*(e2-2dot), trunc
            int key = (int)(((unsigned)q) << 10) | klane;
            int o1  = b1[r];
            b1[r] = min(o1, key);
            b2[r] = min(max(o1, key), b2[r]);               // v_med3_i32 (b1<=b2 invariant)
        }
        cur ^= 1;
    }

    // ---- cross-lane reduction (per half-wave = 32 lanes sharing a row) ----
    int sm1 = 0x7FFFFFFF, sm2 = 0x7FFFFFFF, sc = 1;
    unsigned long long hm = (lane < 32) ? 0xFFFFFFFFull : 0xFFFFFFFF00000000ull;
    #pragma unroll
    for (int r = 0; r < 16; r++) {
        int v1 = b1[r], v2 = b2[r];
        #pragma unroll
        for (int m = 1; m <= 16; m <<= 1) {
            int o1 = __shfl_xor(v1, m, 64);
            int o2 = __shfl_xor(v2, m, 64);
            int lo = min(v1, o1), hi = max(v1, o1);
            v1 = lo;
            v2 = min(min(v2, o2), hi);
        }
        int thr = (v1 >> 10) + 41;   // window = 41/2048 ~= 0.02
        bool in1 = (b1[r] >> 10) <= thr;
        bool in2 = (b2[r] >> 10) <= thr;
        unsigned long long B1 = __ballot(in1), B2 = __ballot(in2);
        int cnt = (int)__popcll(B1 & hm) + (int)__popcll(B2 & hm);
        int w1a = __shfl(v1, 0, 64),  w2a = __shfl(v2, 0, 64),  ca = __shfl(cnt, 0, 64);
        int w1b = __shfl(v1, 32, 64), w2b = __shfl(v2, 32, 64), cb = __shfl(cnt, 32, 64);
        int r0 = (r & 3) + 8 * (r >> 2);   // row of acc reg r (hi=0 half)
        if (lane == r0)     { sm1 = w1a; sm2 = w2a; sc = ca; }
        if (lane == r0 + 4) { sm1 = w1b; sm2 = w2b; sc = cb; }
    }

    int kw = sm1 & 1023;   // meaningful on lanes 0..31 (one lane per row)

    // ---- wave-cooperative exact full scan for sc>=3 rows (rare path).
    // Only lanes 0..31 can be flagged (upper lanes still hold sc=1 init).
    {
        unsigned long long fm = __ballot(sc >= 3);
        while (fm) {
            int j = __ffsll(fm) - 1; fm &= (fm - 1);
            const float4* xr = (const float4*)(x + (size_t)(wbase + j) * DIMV);
            float4 xb[16];
            float xb2 = 0.f;
            #pragma unroll
            for (int i = 0; i < 16; i++) {
                float4 v = xr[i];                 // broadcast load (same addr all lanes)
                xb[i] = v;
                xb2 += v.x * v.x + v.y * v.y + v.z * v.z + v.w * v.w;
            }
            float bd = 3.4e38f; int bc = 0;
            for (int t = 0; t < 16; t++) {
                int c = lane + (t << 6);
                const float4* ep = (const float4*)(et + (c << 6));
                float ax = 0.f, ay = 0.f, az = 0.f, aw = 0.f;
                #pragma unroll 4
                for (int i = 0; i < 16; i++) {
                    float4 ev = ep[i];
                    ax = fmaf(xb[i].x, ev.x, ax);
                    ay = fmaf(xb[i].y, ev.y, ay);
                    az = fmaf(xb[i].z, ev.z, az);
                    aw = fmaf(xb[i].w, ev.w, aw);
                }
                float dot = (ax + ay) + (az + aw);
                float d = (xb2 - 2.0f * dot) + e2g[c];
                if (d < bd) { bd = d; bc = c; }   // ascending c: lowest idx on ties
            }
            #pragma unroll
            for (int m = 1; m < 64; m <<= 1) {    // lexicographic (dist, idx) min
                float od = __shfl_xor(bd, m, 64);
                int   oc = __shfl_xor(bc, m, 64);
                if (od < bd || (od == bd && oc < bc)) { bd = od; bc = oc; }
            }
            if (lane == j) kw = bc;
        }
    }

    // ---- broadcast per-row results from owner lane (lane&31) to both halves ----
    kw  = __shfl(kw,  lm, 64);
    sm2 = __shfl(sm2, lm, 64);
    sc  = __shfl(sc,  lm, 64);

    // ---- split-half epilogue: lane handles dims [lh*32, lh*32+32) of row wbase+lm ----
    const int row = wbase + lm;
    const bool valid = (mask[row] == 0);   // valid = ~mask

    float4 xc[8];
    {
        const float4* xp = (const float4*)(x + (size_t)row * DIMV + lh * 32);
        #pragma unroll
        for (int i = 0; i < 8; i++) xc[i] = xp[i];
    }

    if (sc == 2) {
        // exact recheck of the two candidates; half-dots combined across the lane pair
        float x2h = 0.f;
        #pragma unroll
        for (int i = 0; i < 8; i++)
            x2h += xc[i].x * xc[i].x + xc[i].y * xc[i].y + xc[i].z * xc[i].z + xc[i].w * xc[i].w;

        auto doth = [&](int k) -> float {
            const float4* ep = (const float4*)(et + (k << 6) + lh * 32);
            float ax = 0.f, ay = 0.f, az = 0.f, aw = 0.f;
            #pragma unroll
            for (int i = 0; i < 8; i++) {
                float4 ev = ep[i];
                ax = fmaf(xc[i].x, ev.x, ax);
                ay = fmaf(xc[i].y, ev.y, ay);
                az = fmaf(xc[i].z, ev.z, az);
                aw = fmaf(xc[i].w, ev.w, aw);
            }
            return (ax + ay) + (az + aw);
        };

        int k2 = sm2 & 1023;
        float p1 = x2h - 2.0f * doth(kw);
        float p2 = x2h - 2.0f * doth(k2);
        p1 += __shfl_xor(p1, 32, 64);   // combine halves (commutative -> identical on pair)
        p2 += __shfl_xor(p2, 32, 64);
        float d1 = p1 + e2g[kw];
        float d2 = p2 + e2g[k2];
        if (d2 < d1 || (d2 == d1 && k2 < kw)) kw = k2;
    }

    float sqh = 0.f;
    float4* qp = (float4*)(out + OQ + (size_t)row * DIMV + lh * 32);
    const float4* erow = (const float4*)(et + (kw << 6) + lh * 32);
    #pragma unroll
    for (int i = 0; i < 8; i++) {
        float4 xvv = xc[i];
        float4 ev  = erow[i];
        float q0 = xvv.x + (ev.x - xvv.x);
        float q1 = xvv.y + (ev.y - xvv.y);
        float q2 = xvv.z + (ev.z - xvv.z);
        float q3 = xvv.w + (ev.w - xvv.w);
        float4 q4 = {q0, q1, q2, q3};
        qp[i] = q4;
        float d0 = q0 - xvv.x, d1 = q1 - xvv.y, d2 = q2 - xvv.z, d3 = q3 - xvv.w;
        sqh += d0 * d0 + d1 * d1 + d2 * d2 + d3 * d3;
    }

    // per-row code record: ONE plain coalesced 2B store (row owner half), no atomics.
    if (lh == 0) kwv[row] = valid ? (unsigned short)kw : (unsigned short)0xFFFF;

    // per-block loss partial: each lane contributes its half-row sq; wave sum covers rows.
    float v = valid ? sqh : 0.0f;
    #pragma unroll
    for (int off = 32; off > 0; off >>= 1) v += __shfl_down(v, off, 64);
    if (lane == 0) lw[wid] = v;
    __syncthreads();
    if (tid == 0) loss_part[blockIdx.x] = (lw[0] + lw[1]) + (lw[2] + lw[3]);
}

// ---------------------------------------------------------------- bucket append (dedicated kernel).
// Cursors sharded 8x by source block: cnt[c + 1024*s]. Overflow: fire-and-forget
// fp atomics into pre-zeroed esum (rare, correct for any skew).
__global__ __launch_bounds__(256) void vq_bucket(
    const unsigned short* __restrict__ kwv, const float* __restrict__ x,
    int* __restrict__ cnt, int* __restrict__ bucket,
    float* __restrict__ esum, int capS)
{
    int row = blockIdx.x * 256 + threadIdx.x;
    unsigned short c = kwv[row];
    if (c == 0xFFFFu) return;
    int s = blockIdx.x & (NSH - 1);
    int pos = atomicAdd(&cnt[(int)c + (s << 10)], 1);
    if (pos < capS) {
        bucket[((size_t)s * NEMB + (int)c) * capS + pos] = row;
    } else {
        const float* xr = x + (size_t)row * DIMV;
        float* ep = esum + ((int)c << 6);
        #pragma unroll 8
        for (int i = 0; i < DIMV; i++) atomicAdd(ep + i, xr[i]);
    }
}

// ---------------------------------------------------------------- per-code gather-sum.
// Block per code, 8 waves; wave w owns shard w. 8-deep load ILP, fully-coalesced
// 256B row reads (d = lane). esum '+=' keeps overflow-path atomic contributions.
__global__ __launch_bounds__(512) void vq_esum(
    const float* __restrict__ x, const int* __restrict__ cnt,
    const int* __restrict__ bucket, float* __restrict__ esum, int capS)
{
    const int tid  = threadIdx.x;
    const int lane = tid & 63;
    const int wid  = tid >> 6;      // 0..7 = shard
    const int c    = blockIdx.x;
    const int n    = min(cnt[c + (wid << 10)], capS);
    const int* bp  = bucket + ((size_t)wid * NEMB + c) * capS;
    __shared__ float part[8][64];

    float acc = 0.f;
    for (int i = 0; i < n; i += 8) {
        float tmp[8];
        if (i + 8 <= n) {
            // bulk: two 16B broadcast loads of 8 contiguous row-ids (capS is 8-aligned)
            int4 a = *(const int4*)(bp + i);
            int4 b = *(const int4*)(bp + i + 4);
            tmp[0] = x[(size_t)a.x * DIMV + lane];
            tmp[1] = x[(size_t)a.y * DIMV + lane];
            tmp[2] = x[(size_t)a.z * DIMV + lane];
            tmp[3] = x[(size_t)a.w * DIMV + lane];
            tmp[4] = x[(size_t)b.x * DIMV + lane];
            tmp[5] = x[(size_t)b.y * DIMV + lane];
            tmp[6] = x[(size_t)b.z * DIMV + lane];
            tmp[7] = x[(size_t)b.w * DIMV + lane];
        } else {
            #pragma unroll
            for (int k = 0; k < 8; k++) {
                int idx = i + k;
                tmp[k] = (idx < n) ? x[(size_t)bp[idx] * DIMV + lane] : 0.f;
            }
        }
        acc += ((tmp[0] + tmp[1]) + (tmp[2] + tmp[3]))
             + ((tmp[4] + tmp[5]) + (tmp[6] + tmp[7]));
    }

    part[wid][lane] = acc;
    __syncthreads();
    if (tid < 64) {
        float s = 0.f;
        #pragma unroll
        for (int w = 0; w < 8; w++) s += part[w][lane];
        esum[(c << 6) + lane] += s;   // += keeps overflow atomics (esum pre-zeroed)
    }
}

// ---------------------------------------------------------------- finalize A
// counts = sum of 8 shard cursors; loss = tree-reduce of 2048 per-block partials.
__global__ __launch_bounds__(1024) void vq_finalA(
    const float* __restrict__ cluster_size, const int* __restrict__ cnt,
    const float* __restrict__ loss_part, float* __restrict__ out,
    float* __restrict__ total_ws)
{
    __shared__ float s1[1024];
    __shared__ float s2[1024];
    __shared__ float s3[1024];
    int k = threadIdx.x;
    int ci = 0;
    #pragma unroll
    for (int s = 0; s < NSH; s++) ci += cnt[k + (s << 10)];
    float c   = (float)ci;
    float ncs = cluster_size[k] * DECAYF + OMDF * c;
    out[ONC + k] = ncs;
    s1[k] = ncs; s2[k] = c; s3[k] = loss_part[k] + loss_part[k + 1024];
    __syncthreads();
    for (int off = 512; off > 0; off >>= 1) {
        if (k < off) { s1[k] += s1[k + off]; s2[k] += s2[k + off]; s3[k] += s3[k + off]; }
        __syncthreads();
    }
    if (k == 0) {
        total_ws[0] = s1[0];
        out[OL] = s3[0] / (s2[0] * (float)DIMV);
    }
}

// ---------------------------------------------------------------- finalize B (esum is k-major)
__global__ void vq_finalB(const float* __restrict__ embed_avg,
                          const float* __restrict__ esum,
                          float* __restrict__ out,
                          const float* __restrict__ total_ws)
{
    int idx = blockIdx.x * 256 + threadIdx.x;  // < 65536, idx = d*1024 + k
    int k = idx & (NEMB - 1);
    int d = idx >> 10;
    float avg = embed_avg[idx] * DECAYF + OMDF * esum[(k << 6) + d];
    out[OA + idx] = avg;
    float ncs   = out[ONC + k];
    float total = *total_ws;
    float sm = (ncs + EPSF) / (total + (float)NEMB * EPSF) * total;
    out[OE + idx] = avg / sm;
}

// ---------------------------------------------------------------- launcher
extern "C" void kernel_launch(void* const* d_in, const int* in_sizes, int n_in,
                              void* d_out, int out_size, void* d_ws, size_t ws_size,
                              hipStream_t stream)
{
    const float* x            = (const float*)d_in[0];
    const int*   mask         = (const int*)d_in[1];
    const float* embed        = (const float*)d_in[2];
    const float* cluster_size = (const float*)d_in[3];
    const float* embed_avg    = (const float*)d_in[4];
    float* out = (float*)d_out;
    float* ws  = (float*)d_ws;

    unsigned short* eh     = (unsigned short*)(out + OEH);
    unsigned short* el     = (unsigned short*)(out + OEL);
    unsigned short* kwv    = (unsigned short*)(ws + WS_KWV);
    int*            cnt    = (int*)(ws + WS_CNT);
    int*            bucket = (int*)(ws + WS_BUCKET);

    // per-shard bucket capacity from available workspace (8-aligned for int4 reads);
    // capS == 0 -> all rows take the overflow-atomic path (slow but correct).
    int capS = 0;
    size_t avail = ws_size / sizeof(float);
    if (avail > (size_t)WS_BUCKET) {
        size_t per = (avail - (size_t)WS_BUCKET) / ((size_t)NEMB * NSH);
        if (per > 768) per = 768;
        capS = (int)per & ~7;
    }

    // zero cursors + esum (loss partials are fully overwritten by vq_main)
    hipMemsetAsync(ws + WS_CNT, 0, (size_t)(WS_LOSSP - WS_CNT) * sizeof(float), stream);

    vq_prep<<<65536 / 256, 256, 0, stream>>>(embed, ws + WS_ET, eh, el);
    vq_e2<<<NEMB / 256, 256, 0, stream>>>(ws + WS_ET, ws + WS_E2);
    vq_main<<<NROWS / 128, 256, 0, stream>>>(x, mask, eh, el, ws + WS_ET, ws + WS_E2,
                                             out, kwv, ws + WS_LOSSP);
    vq_bucket<<<NROWS / 256, 256, 0, stream>>>(kwv, x, cnt, bucket, ws + WS_ESUM, capS);
    vq_esum<<<NEMB, 512, 0, stream>>>(x, cnt, bucket, ws + WS_ESUM, capS);
    vq_finalA<<<1, 1024, 0, stream>>>(cluster_size, cnt, ws + WS_LOSSP,
                                      out, ws + WS_TOTAL);
    vq_finalB<<<65536 / 256, 256, 0, stream>>>(embed_avg, ws + WS_ESUM, out, ws + WS_TOTAL);
}